// Round 7
// baseline (235.749 us; speedup 1.0000x reference)
//
#include <hip/hip_runtime.h>
#include <stdint.h>
#include <stddef.h>

typedef __bf16 bf16_t;
typedef bf16_t bf16x4 __attribute__((ext_vector_type(4)));
typedef bf16_t bf16x8 __attribute__((ext_vector_type(8)));
typedef float f32x4 __attribute__((ext_vector_type(4)));

#define MFMA_BF16(A_, B_, C_) __builtin_amdgcn_mfma_f32_16x16x32_bf16(A_, B_, C_, 0, 0, 0)

static constexpr int Lseq = 2048;
static constexpr int Dmod = 1024;
static constexpr int Hn   = 16;
static constexpr int HDim = 64;
static constexpr size_t M1 = 1u << 20;  // 1M elements

// XOR-swizzled offset (elements) into a [rows][64] bf16 tile, 16B chunks
__device__ __forceinline__ int swz(int row, int chunk) {
  return row * 64 + ((chunk ^ (row & 7)) << 3);
}

// async global->LDS DMA, 16B per lane, wave-uniform LDS base
__device__ __forceinline__ void async_ld16(const bf16_t* g, bf16_t* l) {
  __builtin_amdgcn_global_load_lds(
      (const __attribute__((address_space(1))) void*)g,
      (__attribute__((address_space(3))) void*)l, 16, 0, 0);
}

// ---------------------------------------------------------------------------
// cvt_kernel: fp32 -> bf16, 16B stores. wq additionally pre-scaled by
// 0.125*log2(e) so attention scores arrive ready for exp2 (no per-elem mul).
// ---------------------------------------------------------------------------
__global__ __launch_bounds__(256) void cvt_kernel(
    const float* __restrict__ Q, const float* __restrict__ K,
    const float* __restrict__ V, const float* __restrict__ wq,
    const float* __restrict__ wk, const float* __restrict__ wv,
    const float* __restrict__ wout, bf16_t* __restrict__ wsb)
{
  const int s = blockIdx.z;
  const float* __restrict__ src;
  if      (s < 4)   src = Q    + (size_t)s * M1;
  else if (s < 8)   src = K    + (size_t)(s - 4) * M1;
  else if (s < 12)  src = V    + (size_t)(s - 8) * M1;
  else if (s == 12) src = wq;
  else if (s == 13) src = wk;
  else if (s == 14) src = wv;
  else              src = wout;
  bf16_t* __restrict__ dst = wsb + (size_t)s * M1;
  const float scale = (s == 12) ? 0.18033688f : 1.0f;  // 0.125 * log2(e)

  const int idx = blockIdx.x * 256 + threadIdx.x;  // 0..131071 (1M/8)
  float4 a = ((const float4*)src)[idx * 2];
  float4 b = ((const float4*)src)[idx * 2 + 1];
  bf16x8 o;
  o[0] = (bf16_t)(a.x * scale); o[1] = (bf16_t)(a.y * scale);
  o[2] = (bf16_t)(a.z * scale); o[3] = (bf16_t)(a.w * scale);
  o[4] = (bf16_t)(b.x * scale); o[5] = (bf16_t)(b.y * scale);
  o[6] = (bf16_t)(b.z * scale); o[7] = (bf16_t)(b.w * scale);
  ((bf16x8*)dst)[idx] = o;
}

// ---------------------------------------------------------------------------
// proj_kernel: all-bf16 GEMM P = X @ W^T. R20: 128x64 tile, BK=64, 1536
// blocks (6/CU, TLP-hidden) — but B FRAGMENTS READ DIRECT FROM GLOBAL
// (L1/L2-resident weight panel), Bs LDS deleted. Diagnosis: proj is
// LDS-BW-bound (72 KB LDS traffic per block-K-step vs ~78 cyc of MFMA);
// removing B's LDS write+2x-amplified read cuts traffic 33% and shortens
// the DMA drain 6->4 loads. VMEM B-loads overlap lgkm A-reads.
//   z=0 -> q [B,H,L,HD]; z=1 -> k [B,H,L,HD]; z=2 -> v [B,H,HD,L]
// ---------------------------------------------------------------------------
__global__ __launch_bounds__(256) void proj_kernel(
    const bf16_t* __restrict__ Qbf, const bf16_t* __restrict__ Kbf,
    const bf16_t* __restrict__ Vbf, const bf16_t* __restrict__ wqb,
    const bf16_t* __restrict__ wkb, const bf16_t* __restrict__ wvb,
    bf16_t* __restrict__ qo, bf16_t* __restrict__ ko, bf16_t* __restrict__ vo)
{
  const int z = blockIdx.z;
  const bf16_t* __restrict__ A  = (z == 0) ? Qbf : (z == 1) ? Kbf : Vbf;
  const bf16_t* __restrict__ Bw = (z == 0) ? wqb : (z == 1) ? wkb : wvb;
  bf16_t* __restrict__ dst      = (z == 0) ? qo  : (z == 1) ? ko  : vo;

  __shared__ __align__(16) bf16_t As[128 * 64];  // 16 KB (Bs deleted)

  const int tid  = threadIdx.x;
  const int wave = tid >> 6;
  const int lane = tid & 63;
  const int quad = lane >> 4;
  const int l16  = lane & 15;
  const int wm   = (wave & 1) * 64;
  const int wn   = (wave >> 1) * 32;
  const int m0   = blockIdx.x * 128;   // x = m (32): same-A blocks -> same XCD
  const int n0   = blockIdx.y * 64;    // y = n (16)

  const int srow8  = lane >> 3;
  const int schunk = (lane & 7) ^ srow8;

  // per-lane global base for B-fragment rows (row = n0+wn+nt*16+l16)
  const bf16_t* __restrict__ bwp = Bw + (size_t)(n0 + wn + l16) * Dmod;

  f32x4 acc[4][2];
#pragma unroll
  for (int i = 0; i < 4; ++i)
#pragma unroll
    for (int j = 0; j < 2; ++j)
#pragma unroll
      for (int e = 0; e < 4; ++e) acc[i][j][e] = 0.0f;

  for (int kt = 0; kt < 16; ++kt) {
    const int k0 = kt * 64;
    __syncthreads();  // LDS reads of previous iter done
#pragma unroll
    for (int i = 0; i < 4; ++i) {
      const int rb = wave * 32 + i * 8;
      async_ld16(&A[(size_t)(m0 + rb + srow8) * Dmod + k0 + schunk * 8], &As[rb * 64]);
    }

    // B fragments direct from global (L2-resident weights); issued before
    // the barrier-drain so VMEM latency overlaps the A-DMA drain + ds_reads
    bf16x8 bfr[2][2];
#pragma unroll
    for (int nt = 0; nt < 2; ++nt) {
      bfr[nt][0] = *(const bf16x8*)&bwp[(size_t)(nt * 16) * Dmod + k0 + quad * 8];
      bfr[nt][1] = *(const bf16x8*)&bwp[(size_t)(nt * 16) * Dmod + k0 + 32 + quad * 8];
    }
    __syncthreads();  // A-DMA drained

    bf16x8 af[4][2];
#pragma unroll
    for (int mt = 0; mt < 4; ++mt) {
      const int row = wm + mt * 16 + l16;
      af[mt][0] = *(const bf16x8*)&As[swz(row, quad)];
      af[mt][1] = *(const bf16x8*)&As[swz(row, quad + 4)];
    }
#pragma unroll
    for (int mt = 0; mt < 4; ++mt)
#pragma unroll
      for (int nt = 0; nt < 2; ++nt) {
        acc[mt][nt] = MFMA_BF16(af[mt][0], bfr[nt][0], acc[mt][nt]);
        acc[mt][nt] = MFMA_BF16(af[mt][1], bfr[nt][1], acc[mt][nt]);
      }
  }

#pragma unroll
  for (int mt = 0; mt < 4; ++mt) {
    const int grb = m0 + wm + mt * 16 + quad * 4;
    const int bb  = grb >> 11;
    const int lb  = grb & 2047;
#pragma unroll
    for (int nt = 0; nt < 2; ++nt) {
      const int gc = n0 + wn + nt * 16 + l16;
      const int h  = gc >> 6;
      const int hd = gc & 63;
      if (z == 2) {
        bf16x4 pk;
#pragma unroll
        for (int r = 0; r < 4; ++r) pk[r] = (bf16_t)acc[mt][nt][r];
        *(bf16x4*)&dst[(((size_t)(bb * Hn + h) * HDim + hd) << 11) + lb] = pk;
      } else {
#pragma unroll
        for (int r = 0; r < 4; ++r)
          dst[(((size_t)(bb * Hn + h) * Lseq + lb + r) << 6) + hd] = (bf16_t)acc[mt][nt][r];
      }
    }
  }
}

// ---------------------------------------------------------------------------
// attn_kernel: causal flash attention — R20: 64-row q-blocks (R13's proven
// geometry: 4 waves x 16 q-rows, grid (32,32)=1024 blocks, LDS 41 KB ->
// 3 blocks/CU resident vs R19's grid-limited 2) + T5 setprio around the
// MFMA cluster (R19: +10% measured). dbuf K/V DMA, Ps-LDS P round-trip
// (measured faster than bpermute transpose), LPT, XCD=bh%8.
// ---------------------------------------------------------------------------
__global__ __launch_bounds__(256, 3) void attn_kernel(
    const bf16_t* __restrict__ q, const bf16_t* __restrict__ k,
    const bf16_t* __restrict__ v, bf16_t* __restrict__ ctx)
{
  const int bh = blockIdx.x;            // 0..31  (fast dim -> XCD = bh%8)
  const int qt = 31 - blockIdx.y;       // LPT: longest blocks first
  const int bb = bh >> 4;
  const int h  = bh & 15;
  const int q0 = qt * 64;

  const int tid  = threadIdx.x;
  const int wave = tid >> 6;
  const int lane = tid & 63;
  const int quad = lane >> 4;
  const int l16  = lane & 15;

  __shared__ __align__(16) bf16_t Ks[2][64 * 64];  // 16 KB
  __shared__ __align__(16) bf16_t Vs[2][64 * 64];  // 16 KB
  __shared__ __align__(16) bf16_t Ps[4][16][72];   //  9 KB

  const bf16_t* __restrict__ qb = q + (size_t)bh * (Lseq * HDim);
  const bf16_t* __restrict__ kb = k + (size_t)bh * (Lseq * HDim);
  const bf16_t* __restrict__ vb = v + (size_t)bh * (HDim * Lseq);

  const int srow8  = lane >> 3;
  const int schunk = (lane & 7) ^ srow8;

  bf16x8 ones;
#pragma unroll
  for (int i = 0; i < 8; ++i) ones[i] = (bf16_t)1.0f;

  const int qlo = q0 + wave * 16;       // wave's first query row
  const int qrow = qlo + l16;
  bf16x8 qf0 = *(const bf16x8*)&qb[(size_t)qrow * HDim + quad * 8];
  bf16x8 qf1 = *(const bf16x8*)&qb[(size_t)qrow * HDim + 32 + quad * 8];

  // strength-reduced per-lane DMA source pointers (advance per k-tile)
  const bf16_t* ks0 = kb + (size_t)(wave * 16 + srow8) * HDim + schunk * 8;
  const bf16_t* ks1 = ks0 + (size_t)8 * HDim;
  const bf16_t* vs0 = vb + (size_t)(wave * 16 + srow8) * Lseq + schunk * 8;
  const bf16_t* vs1 = vs0 + (size_t)8 * Lseq;
  const int ldo0 = (wave * 16) * 64;
  const int ldo1 = (wave * 16 + 8) * 64;

  // hoisted swizzled LDS read offsets (same rows for Ks and Vs)
  int ro0[4], ro1[4];
#pragma unroll
  for (int nt = 0; nt < 4; ++nt) {
    const int row = nt * 16 + l16;
    ro0[nt] = swz(row, quad);
    ro1[nt] = swz(row, quad + 4);
  }

  f32x4 o[4];
  f32x4 lacc;
#pragma unroll
  for (int e = 0; e < 4; ++e) lacc[e] = 0.0f;
#pragma unroll
  for (int nt = 0; nt < 4; ++nt)
#pragma unroll
    for (int e = 0; e < 4; ++e) o[nt][e] = 0.0f;

  // preload tile jt=0 into buffer 0
  async_ld16(ks0, &Ks[0][ldo0]);
  async_ld16(ks1, &Ks[0][ldo1]);
  async_ld16(vs0, &Vs[0][ldo0]);
  async_ld16(vs1, &Vs[0][ldo1]);
  ks0 += (size_t)64 * HDim; ks1 += (size_t)64 * HDim;
  vs0 += 64;                vs1 += 64;

  for (int jt = 0; jt <= qt; ++jt) {
    const int cur = jt & 1;
    __syncthreads();  // drains cur's DMA; alt's readers (iter jt-1) done

    if (jt < qt) {    // prefetch next tile into alt; in flight under compute
      async_ld16(ks0, &Ks[cur ^ 1][ldo0]);
      async_ld16(ks1, &Ks[cur ^ 1][ldo1]);
      async_ld16(vs0, &Vs[cur ^ 1][ldo0]);
      async_ld16(vs1, &Vs[cur ^ 1][ldo1]);
      ks0 += (size_t)64 * HDim; ks1 += (size_t)64 * HDim;
      vs0 += 64;                vs1 += 64;
    }

    // S^T = K Q^T  (m=key, n=query); scores pre-scaled for exp2
    if (jt == qt) {   // diagonal tile (only the last one for 64-row blocks)
      const int db = qlo + l16 - jt * 64;  // mask iff key_local > db
#pragma unroll
      for (int nt = 0; nt < 4; ++nt) {
        bf16x8 kf0 = *(const bf16x8*)&Ks[cur][ro0[nt]];
        bf16x8 kf1 = *(const bf16x8*)&Ks[cur][ro1[nt]];
        f32x4 s;
#pragma unroll
        for (int e = 0; e < 4; ++e) s[e] = 0.0f;
        s = MFMA_BF16(kf0, qf0, s);
        s = MFMA_BF16(kf1, qf1, s);
        bf16x4 pk;
#pragma unroll
        for (int r = 0; r < 4; ++r) {
          const int kl = nt * 16 + quad * 4 + r;
          float val = (kl > db) ? -1e30f : s[r];
          pk[r] = (bf16_t)__builtin_amdgcn_exp2f(val);
        }
        *(bf16x4*)&Ps[wave][l16][nt * 16 + quad * 4] = pk;
      }
    } else {
#pragma unroll
      for (int nt = 0; nt < 4; ++nt) {
        bf16x8 kf0 = *(const bf16x8*)&Ks[cur][ro0[nt]];
        bf16x8 kf1 = *(const bf16x8*)&Ks[cur][ro1[nt]];
        f32x4 s;
#pragma unroll
        for (int e = 0; e < 4; ++e) s[e] = 0.0f;
        s = MFMA_BF16(kf0, qf0, s);
        s = MFMA_BF16(kf1, qf1, s);
        bf16x4 pk;
#pragma unroll
        for (int r = 0; r < 4; ++r)
          pk[r] = (bf16_t)__builtin_amdgcn_exp2f(s[r]);
        *(bf16x4*)&Ps[wave][l16][nt * 16 + quad * 4] = pk;
      }
    }

    // P fragments (A-layout) — wave-local LDS round-trip
    bf16x8 pf0 = *(const bf16x8*)&Ps[wave][l16][quad * 8];
    bf16x8 pf1 = *(const bf16x8*)&Ps[wave][l16][32 + quad * 8];

    // dense MFMA cluster: prioritize this wave on the CU scheduler (T5)
    __builtin_amdgcn_s_setprio(1);

    lacc = MFMA_BF16(pf0, ones, lacc);
    lacc = MFMA_BF16(pf1, ones, lacc);

#pragma unroll
    for (int nt = 0; nt < 4; ++nt) {
      bf16x8 vf0 = *(const bf16x8*)&Vs[cur][ro0[nt]];
      bf16x8 vf1 = *(const bf16x8*)&Vs[cur][ro1[nt]];
      o[nt] = MFMA_BF16(pf0, vf0, o[nt]);
      o[nt] = MFMA_BF16(pf1, vf1, o[nt]);
    }

    __builtin_amdgcn_s_setprio(0);
  }

  float inv[4];
#pragma unroll
  for (int r = 0; r < 4; ++r) inv[r] = 1.0f / lacc[r];
#pragma unroll
  for (int nt = 0; nt < 4; ++nt)
#pragma unroll
    for (int r = 0; r < 4; ++r) {
      const int gq = q0 + wave * 16 + quad * 4 + r;
      ctx[(size_t)(bb * Lseq + gq) * Dmod + h * HDim + nt * 16 + l16] =
          (bf16_t)(o[nt][r] * inv[r]);
    }
}

// ---------------------------------------------------------------------------
// out_kernel: OUT = CTX @ Wout^T. R20: 128x64 tile, B fragments direct from
// global (wout is 2 MB, L2-resident), Bs deleted (same LDS-BW rationale as
// proj). Grid (x=m=32, y=n=16). fp32 out.
// ---------------------------------------------------------------------------
__global__ __launch_bounds__(256) void out_kernel(
    const bf16_t* __restrict__ Actx, const bf16_t* __restrict__ Bwout,
    float* __restrict__ out)
{
  __shared__ __align__(16) bf16_t As[128 * 64];  // 16 KB

  const int tid  = threadIdx.x;
  const int wave = tid >> 6;
  const int lane = tid & 63;
  const int quad = lane >> 4;
  const int l16  = lane & 15;
  const int wm   = (wave & 1) * 64;
  const int wn   = (wave >> 1) * 32;
  const int m0   = blockIdx.x * 128;   // x = m: same-A blocks -> same XCD
  const int n0   = blockIdx.y * 64;

  const int srow8  = lane >> 3;
  const int schunk = (lane & 7) ^ srow8;

  const bf16_t* __restrict__ bwp = Bwout + (size_t)(n0 + wn + l16) * Dmod;

  f32x4 acc[4][2];
#pragma unroll
  for (int i = 0; i < 4; ++i)
#pragma unroll
    for (int j = 0; j < 2; ++j)
#pragma unroll
      for (int e = 0; e < 4; ++e) acc[i][j][e] = 0.0f;

  for (int kt = 0; kt < 16; ++kt) {
    const int k0 = kt * 64;
    __syncthreads();
#pragma unroll
    for (int i = 0; i < 4; ++i) {
      const int rb = wave * 32 + i * 8;
      async_ld16(&Actx[(size_t)(m0 + rb + srow8) * Dmod + k0 + schunk * 8], &As[rb * 64]);
    }

    bf16x8 bfr[2][2];
#pragma unroll
    for (int nt = 0; nt < 2; ++nt) {
      bfr[nt][0] = *(const bf16x8*)&bwp[(size_t)(nt * 16) * Dmod + k0 + quad * 8];
      bfr[nt][1] = *(const bf16x8*)&bwp[(size_t)(nt * 16) * Dmod + k0 + 32 + quad * 8];
    }
    __syncthreads();

    bf16x8 af[4][2];
#pragma unroll
    for (int mt = 0; mt < 4; ++mt) {
      const int row = wm + mt * 16 + l16;
      af[mt][0] = *(const bf16x8*)&As[swz(row, quad)];
      af[mt][1] = *(const bf16x8*)&As[swz(row, quad + 4)];
    }
#pragma unroll
    for (int mt = 0; mt < 4; ++mt)
#pragma unroll
      for (int nt = 0; nt < 2; ++nt) {
        acc[mt][nt] = MFMA_BF16(af[mt][0], bfr[nt][0], acc[mt][nt]);
        acc[mt][nt] = MFMA_BF16(af[mt][1], bfr[nt][1], acc[mt][nt]);
      }
  }

#pragma unroll
  for (int mt = 0; mt < 4; ++mt) {
    const int grb = m0 + wm + mt * 16 + quad * 4;
#pragma unroll
    for (int nt = 0; nt < 2; ++nt) {
      const int gc = n0 + wn + nt * 16 + l16;
#pragma unroll
      for (int r = 0; r < 4; ++r)
        out[(size_t)(grb + r) * Dmod + gc] = acc[mt][nt][r];
    }
  }
}

// ---------------------------------------------------------------------------
extern "C" void kernel_launch(void* const* d_in, const int* in_sizes, int n_in,
                              void* d_out, int out_size, void* d_ws, size_t ws_size,
                              hipStream_t stream) {
  (void)in_sizes; (void)n_in; (void)out_size; (void)ws_size;
  const float* Q    = (const float*)d_in[0];
  const float* K    = (const float*)d_in[1];
  const float* V    = (const float*)d_in[2];
  const float* wq   = (const float*)d_in[5];
  const float* wk   = (const float*)d_in[6];
  const float* wv   = (const float*)d_in[7];
  const float* wout = (const float*)d_in[8];
  float* out = (float*)d_out;

  bf16_t* wsb = (bf16_t*)d_ws;
  bf16_t* Qbf   = wsb;
  bf16_t* Kbf   = wsb + 4 * M1;
  bf16_t* Vbf   = wsb + 8 * M1;
  bf16_t* wqb   = wsb + 12 * M1;
  bf16_t* wkb   = wsb + 13 * M1;
  bf16_t* wvb   = wsb + 14 * M1;
  bf16_t* woutb = wsb + 15 * M1;
  bf16_t* qp    = wsb + 16 * M1;
  bf16_t* kp    = wsb + 20 * M1;
  bf16_t* vp    = wsb + 24 * M1;
  bf16_t* cws   = wsb;  // ctx reuses Qbf region (Qbf dead after proj)

  cvt_kernel<<<dim3(512, 1, 16), 256, 0, stream>>>(Q, K, V, wq, wk, wv, wout, wsb);
  proj_kernel<<<dim3(32, 16, 3), 256, 0, stream>>>(Qbf, Kbf, Vbf, wqb, wkb, wvb, qp, kp, vp);
  attn_kernel<<<dim3(32, 32), 256, 0, stream>>>(qp, kp, vp, cws);
  out_kernel<<<dim3(32, 16), 256, 0, stream>>>(cws, woutb, out);
}

// Round 8
// 211.620 us; speedup vs baseline: 1.1140x; 1.1140x over previous
//
#include <hip/hip_runtime.h>
#include <stdint.h>
#include <stddef.h>

typedef __bf16 bf16_t;
typedef bf16_t bf16x4 __attribute__((ext_vector_type(4)));
typedef bf16_t bf16x8 __attribute__((ext_vector_type(8)));
typedef float f32x4 __attribute__((ext_vector_type(4)));

#define MFMA_BF16(A_, B_, C_) __builtin_amdgcn_mfma_f32_16x16x32_bf16(A_, B_, C_, 0, 0, 0)

static constexpr int Lseq = 2048;
static constexpr int Dmod = 1024;
static constexpr int Hn   = 16;
static constexpr int HDim = 64;
static constexpr size_t M1 = 1u << 20;  // 1M elements

// XOR-swizzled offset (elements) into a [rows][64] bf16 tile, 16B chunks
__device__ __forceinline__ int swz(int row, int chunk) {
  return row * 64 + ((chunk ^ (row & 7)) << 3);
}

// async global->LDS DMA, 16B per lane, wave-uniform LDS base
__device__ __forceinline__ void async_ld16(const bf16_t* g, bf16_t* l) {
  __builtin_amdgcn_global_load_lds(
      (const __attribute__((address_space(1))) void*)g,
      (__attribute__((address_space(3))) void*)l, 16, 0, 0);
}

// ---------------------------------------------------------------------------
// cvt_kernel: fp32 -> bf16, 16B stores. wq additionally pre-scaled by
// 0.125*log2(e) so attention scores arrive ready for exp2 (no per-elem mul).
// ---------------------------------------------------------------------------
__global__ __launch_bounds__(256) void cvt_kernel(
    const float* __restrict__ Q, const float* __restrict__ K,
    const float* __restrict__ V, const float* __restrict__ wq,
    const float* __restrict__ wk, const float* __restrict__ wv,
    const float* __restrict__ wout, bf16_t* __restrict__ wsb)
{
  const int s = blockIdx.z;
  const float* __restrict__ src;
  if      (s < 4)   src = Q    + (size_t)s * M1;
  else if (s < 8)   src = K    + (size_t)(s - 4) * M1;
  else if (s < 12)  src = V    + (size_t)(s - 8) * M1;
  else if (s == 12) src = wq;
  else if (s == 13) src = wk;
  else if (s == 14) src = wv;
  else              src = wout;
  bf16_t* __restrict__ dst = wsb + (size_t)s * M1;
  const float scale = (s == 12) ? 0.18033688f : 1.0f;  // 0.125 * log2(e)

  const int idx = blockIdx.x * 256 + threadIdx.x;  // 0..131071 (1M/8)
  float4 a = ((const float4*)src)[idx * 2];
  float4 b = ((const float4*)src)[idx * 2 + 1];
  bf16x8 o;
  o[0] = (bf16_t)(a.x * scale); o[1] = (bf16_t)(a.y * scale);
  o[2] = (bf16_t)(a.z * scale); o[3] = (bf16_t)(a.w * scale);
  o[4] = (bf16_t)(b.x * scale); o[5] = (bf16_t)(b.y * scale);
  o[6] = (bf16_t)(b.z * scale); o[7] = (bf16_t)(b.w * scale);
  ((bf16x8*)dst)[idx] = o;
}

// ---------------------------------------------------------------------------
// proj_kernel: all-bf16 GEMM P = X @ W^T. R21 = R19 exact (measured-best:
// 43.6 µs, 128x64 tile, BK=64, single-buffered LDS DMA, 1536 blocks = 6/CU,
// TLP-hidden). R20's direct-global B read regressed to 67 µs: per-lane
// 16B reads scattered across 16 rows x 2KB stride = uncoalesced VMEM on the
// K-step critical path. LDS staging IS the coalescer — keep it.
//   z=0 -> q [B,H,L,HD]; z=1 -> k [B,H,L,HD]; z=2 -> v [B,H,HD,L]
// ---------------------------------------------------------------------------
__global__ __launch_bounds__(256) void proj_kernel(
    const bf16_t* __restrict__ Qbf, const bf16_t* __restrict__ Kbf,
    const bf16_t* __restrict__ Vbf, const bf16_t* __restrict__ wqb,
    const bf16_t* __restrict__ wkb, const bf16_t* __restrict__ wvb,
    bf16_t* __restrict__ qo, bf16_t* __restrict__ ko, bf16_t* __restrict__ vo)
{
  const int z = blockIdx.z;
  const bf16_t* __restrict__ A  = (z == 0) ? Qbf : (z == 1) ? Kbf : Vbf;
  const bf16_t* __restrict__ Bw = (z == 0) ? wqb : (z == 1) ? wkb : wvb;
  bf16_t* __restrict__ dst      = (z == 0) ? qo  : (z == 1) ? ko  : vo;

  __shared__ __align__(16) bf16_t As[128 * 64];  // 16 KB
  __shared__ __align__(16) bf16_t Bs[64 * 64];   //  8 KB

  const int tid  = threadIdx.x;
  const int wave = tid >> 6;
  const int lane = tid & 63;
  const int quad = lane >> 4;
  const int l16  = lane & 15;
  const int wm   = (wave & 1) * 64;
  const int wn   = (wave >> 1) * 32;
  const int m0   = blockIdx.x * 128;   // x = m (32): same-A blocks -> same XCD
  const int n0   = blockIdx.y * 64;    // y = n (16)

  const int srow8  = lane >> 3;
  const int schunk = (lane & 7) ^ srow8;

  f32x4 acc[4][2];
#pragma unroll
  for (int i = 0; i < 4; ++i)
#pragma unroll
    for (int j = 0; j < 2; ++j)
#pragma unroll
      for (int e = 0; e < 4; ++e) acc[i][j][e] = 0.0f;

  for (int kt = 0; kt < 16; ++kt) {
    const int k0 = kt * 64;
    __syncthreads();  // LDS reads of previous iter done
#pragma unroll
    for (int i = 0; i < 4; ++i) {
      const int rb = wave * 32 + i * 8;
      async_ld16(&A[(size_t)(m0 + rb + srow8) * Dmod + k0 + schunk * 8], &As[rb * 64]);
    }
#pragma unroll
    for (int i = 0; i < 2; ++i) {
      const int rb = wave * 16 + i * 8;
      async_ld16(&Bw[(size_t)(n0 + rb + srow8) * Dmod + k0 + schunk * 8], &Bs[rb * 64]);
    }
    __syncthreads();  // DMA drained

    bf16x8 af[4][2], bfr[2][2];
#pragma unroll
    for (int mt = 0; mt < 4; ++mt) {
      const int row = wm + mt * 16 + l16;
      af[mt][0] = *(const bf16x8*)&As[swz(row, quad)];
      af[mt][1] = *(const bf16x8*)&As[swz(row, quad + 4)];
    }
#pragma unroll
    for (int nt = 0; nt < 2; ++nt) {
      const int row = wn + nt * 16 + l16;
      bfr[nt][0] = *(const bf16x8*)&Bs[swz(row, quad)];
      bfr[nt][1] = *(const bf16x8*)&Bs[swz(row, quad + 4)];
    }
#pragma unroll
    for (int mt = 0; mt < 4; ++mt)
#pragma unroll
      for (int nt = 0; nt < 2; ++nt) {
        acc[mt][nt] = MFMA_BF16(af[mt][0], bfr[nt][0], acc[mt][nt]);
        acc[mt][nt] = MFMA_BF16(af[mt][1], bfr[nt][1], acc[mt][nt]);
      }
  }

#pragma unroll
  for (int mt = 0; mt < 4; ++mt) {
    const int grb = m0 + wm + mt * 16 + quad * 4;
    const int bb  = grb >> 11;
    const int lb  = grb & 2047;
#pragma unroll
    for (int nt = 0; nt < 2; ++nt) {
      const int gc = n0 + wn + nt * 16 + l16;
      const int h  = gc >> 6;
      const int hd = gc & 63;
      if (z == 2) {
        bf16x4 pk;
#pragma unroll
        for (int r = 0; r < 4; ++r) pk[r] = (bf16_t)acc[mt][nt][r];
        *(bf16x4*)&dst[(((size_t)(bb * Hn + h) * HDim + hd) << 11) + lb] = pk;
      } else {
#pragma unroll
        for (int r = 0; r < 4; ++r)
          dst[(((size_t)(bb * Hn + h) * Lseq + lb + r) << 6) + hd] = (bf16_t)acc[mt][nt][r];
      }
    }
  }
}

// ---------------------------------------------------------------------------
// attn_kernel: causal flash attention — R21 = R19 (4 waves x 32 q-rows,
// 128-row q-blocks, dbuf K/V DMA, Ps-LDS round-trip, setprio: 41.0 µs
// measured) + COMPLEMENTARY BLOCK PAIRING. 512 blocks = exactly 2/CU;
// round-robin dispatch puts block i and i+256 on the SAME CU. Old map
// (qt=15-y) paired (15-c/32, 7-c/32): CU tile-counts 24..10 -> makespan 24.
// New map qt = (y<8) ? 15-y : y-8 pairs (q, 15-q): every CU does exactly
// 17 tiles. Predicted -25-29% on attn critical path, zero other changes.
// ---------------------------------------------------------------------------
__global__ __launch_bounds__(256, 2) void attn_kernel(
    const bf16_t* __restrict__ q, const bf16_t* __restrict__ k,
    const bf16_t* __restrict__ v, bf16_t* __restrict__ ctx)
{
  const int bh = blockIdx.x;            // 0..31  (fast dim -> XCD = bh%8)
  const int y  = blockIdx.y;
  const int qt = (y < 8) ? (15 - y) : (y - 8);  // complementary pairing
  const int bb = bh >> 4;
  const int h  = bh & 15;
  const int q0 = qt * 128;

  const int tid  = threadIdx.x;
  const int wave = tid >> 6;
  const int lane = tid & 63;
  const int quad = lane >> 4;
  const int l16  = lane & 15;

  __shared__ __align__(16) bf16_t Ks[2][64 * 64];   // 16 KB
  __shared__ __align__(16) bf16_t Vs[2][64 * 64];   // 16 KB
  __shared__ __align__(16) bf16_t Ps[4][2][16][72]; // 18 KB (2 q-groups)

  const bf16_t* __restrict__ qb = q + (size_t)bh * (Lseq * HDim);
  const bf16_t* __restrict__ kb = k + (size_t)bh * (Lseq * HDim);
  const bf16_t* __restrict__ vb = v + (size_t)bh * (HDim * Lseq);

  const int srow8  = lane >> 3;
  const int schunk = (lane & 7) ^ srow8;

  bf16x8 ones;
#pragma unroll
  for (int i = 0; i < 8; ++i) ones[i] = (bf16_t)1.0f;

  const int qlo = q0 + wave * 32;       // wave's first query row
  const int qhi = qlo + 31;             // wave's last query row

  // Q fragments for both 16-row groups (held in registers for whole kernel)
  const int qrow0 = qlo + l16;
  bf16x8 qf00 = *(const bf16x8*)&qb[(size_t)qrow0 * HDim + quad * 8];
  bf16x8 qf01 = *(const bf16x8*)&qb[(size_t)qrow0 * HDim + 32 + quad * 8];
  bf16x8 qf10 = *(const bf16x8*)&qb[(size_t)(qrow0 + 16) * HDim + quad * 8];
  bf16x8 qf11 = *(const bf16x8*)&qb[(size_t)(qrow0 + 16) * HDim + 32 + quad * 8];

  // strength-reduced per-lane DMA source pointers (advance per k-tile)
  const bf16_t* ks0 = kb + (size_t)(wave * 16 + srow8) * HDim + schunk * 8;
  const bf16_t* ks1 = ks0 + (size_t)8 * HDim;
  const bf16_t* vs0 = vb + (size_t)(wave * 16 + srow8) * Lseq + schunk * 8;
  const bf16_t* vs1 = vs0 + (size_t)8 * Lseq;
  const int ldo0 = (wave * 16) * 64;
  const int ldo1 = (wave * 16 + 8) * 64;

  // hoisted swizzled LDS read offsets (same rows for Ks and Vs)
  int ro0[4], ro1[4];
#pragma unroll
  for (int nt = 0; nt < 4; ++nt) {
    const int row = nt * 16 + l16;
    ro0[nt] = swz(row, quad);
    ro1[nt] = swz(row, quad + 4);
  }

  f32x4 o0[4], o1[4];
  f32x4 lacc0, lacc1;
#pragma unroll
  for (int e = 0; e < 4; ++e) { lacc0[e] = 0.0f; lacc1[e] = 0.0f; }
#pragma unroll
  for (int nt = 0; nt < 4; ++nt)
#pragma unroll
    for (int e = 0; e < 4; ++e) { o0[nt][e] = 0.0f; o1[nt][e] = 0.0f; }

  // preload tile jt=0 into buffer 0
  async_ld16(ks0, &Ks[0][ldo0]);
  async_ld16(ks1, &Ks[0][ldo1]);
  async_ld16(vs0, &Vs[0][ldo0]);
  async_ld16(vs1, &Vs[0][ldo1]);
  ks0 += (size_t)64 * HDim; ks1 += (size_t)64 * HDim;
  vs0 += 64;                vs1 += 64;

  const int jtmax = 2 * qt + 1;
  for (int jt = 0; jt <= jtmax; ++jt) {
    const int cur = jt & 1;
    __syncthreads();  // drains cur's DMA (issuer waits vmcnt before barrier)
                      // and guarantees alt's readers (iter jt-1) are done

    if (jt < jtmax) { // prefetch next tile into alt; in flight under compute
      async_ld16(ks0, &Ks[cur ^ 1][ldo0]);
      async_ld16(ks1, &Ks[cur ^ 1][ldo1]);
      async_ld16(vs0, &Vs[cur ^ 1][ldo0]);
      async_ld16(vs1, &Vs[cur ^ 1][ldo1]);
      ks0 += (size_t)64 * HDim; ks1 += (size_t)64 * HDim;
      vs0 += 64;                vs1 += 64;
    }

    if (jt * 64 <= qhi) {  // wave-uniform: skip fully-masked tiles
      const bool diag = (jt * 64 + 63 > qlo);  // some keys exceed some queries

      // S^T = K Q^T per nt-subtile; kf read once, feeds BOTH q-groups.
      // exp2 + pack fused per-nt (scores pre-scaled for exp2).
      if (diag) {
        const int db0 = qlo + l16 - jt * 64;  // mask iff key_local > db (g=0)
        const int db1 = db0 + 16;             // g=1
#pragma unroll
        for (int nt = 0; nt < 4; ++nt) {
          bf16x8 kf0 = *(const bf16x8*)&Ks[cur][ro0[nt]];
          bf16x8 kf1 = *(const bf16x8*)&Ks[cur][ro1[nt]];
          f32x4 s0, s1;
#pragma unroll
          for (int e = 0; e < 4; ++e) { s0[e] = 0.0f; s1[e] = 0.0f; }
          s0 = MFMA_BF16(kf0, qf00, s0);
          s0 = MFMA_BF16(kf1, qf01, s0);
          s1 = MFMA_BF16(kf0, qf10, s1);
          s1 = MFMA_BF16(kf1, qf11, s1);
          bf16x4 p0, p1;
#pragma unroll
          for (int r = 0; r < 4; ++r) {
            const int kl = nt * 16 + quad * 4 + r;
            float v0 = (kl > db0) ? -1e30f : s0[r];
            float v1 = (kl > db1) ? -1e30f : s1[r];
            p0[r] = (bf16_t)__builtin_amdgcn_exp2f(v0);
            p1[r] = (bf16_t)__builtin_amdgcn_exp2f(v1);
          }
          *(bf16x4*)&Ps[wave][0][l16][nt * 16 + quad * 4] = p0;
          *(bf16x4*)&Ps[wave][1][l16][nt * 16 + quad * 4] = p1;
        }
      } else {
#pragma unroll
        for (int nt = 0; nt < 4; ++nt) {
          bf16x8 kf0 = *(const bf16x8*)&Ks[cur][ro0[nt]];
          bf16x8 kf1 = *(const bf16x8*)&Ks[cur][ro1[nt]];
          f32x4 s0, s1;
#pragma unroll
          for (int e = 0; e < 4; ++e) { s0[e] = 0.0f; s1[e] = 0.0f; }
          s0 = MFMA_BF16(kf0, qf00, s0);
          s0 = MFMA_BF16(kf1, qf01, s0);
          s1 = MFMA_BF16(kf0, qf10, s1);
          s1 = MFMA_BF16(kf1, qf11, s1);
          bf16x4 p0, p1;
#pragma unroll
          for (int r = 0; r < 4; ++r) {
            p0[r] = (bf16_t)__builtin_amdgcn_exp2f(s0[r]);
            p1[r] = (bf16_t)__builtin_amdgcn_exp2f(s1[r]);
          }
          *(bf16x4*)&Ps[wave][0][l16][nt * 16 + quad * 4] = p0;
          *(bf16x4*)&Ps[wave][1][l16][nt * 16 + quad * 4] = p1;
        }
      }

      // P fragments (A-layout) — wave-local LDS round-trip, both groups
      bf16x8 pf00 = *(const bf16x8*)&Ps[wave][0][l16][quad * 8];
      bf16x8 pf01 = *(const bf16x8*)&Ps[wave][0][l16][32 + quad * 8];
      bf16x8 pf10 = *(const bf16x8*)&Ps[wave][1][l16][quad * 8];
      bf16x8 pf11 = *(const bf16x8*)&Ps[wave][1][l16][32 + quad * 8];

      // dense MFMA cluster: prioritize this wave on the CU scheduler (T5)
      __builtin_amdgcn_s_setprio(1);

      lacc0 = MFMA_BF16(pf00, ones, lacc0);
      lacc0 = MFMA_BF16(pf01, ones, lacc0);
      lacc1 = MFMA_BF16(pf10, ones, lacc1);
      lacc1 = MFMA_BF16(pf11, ones, lacc1);

      // PV: vf read once per nt, feeds BOTH q-groups
#pragma unroll
      for (int nt = 0; nt < 4; ++nt) {
        bf16x8 vf0 = *(const bf16x8*)&Vs[cur][ro0[nt]];
        bf16x8 vf1 = *(const bf16x8*)&Vs[cur][ro1[nt]];
        o0[nt] = MFMA_BF16(pf00, vf0, o0[nt]);
        o0[nt] = MFMA_BF16(pf01, vf1, o0[nt]);
        o1[nt] = MFMA_BF16(pf10, vf0, o1[nt]);
        o1[nt] = MFMA_BF16(pf11, vf1, o1[nt]);
      }

      __builtin_amdgcn_s_setprio(0);
    }
  }

  float inv0[4], inv1[4];
#pragma unroll
  for (int r = 0; r < 4; ++r) {
    inv0[r] = 1.0f / lacc0[r];
    inv1[r] = 1.0f / lacc1[r];
  }
#pragma unroll
  for (int nt = 0; nt < 4; ++nt)
#pragma unroll
    for (int r = 0; r < 4; ++r) {
      const int gq0 = q0 + wave * 32 + quad * 4 + r;
      const int gq1 = gq0 + 16;
      ctx[(size_t)(bb * Lseq + gq0) * Dmod + h * HDim + nt * 16 + l16] =
          (bf16_t)(o0[nt][r] * inv0[r]);
      ctx[(size_t)(bb * Lseq + gq1) * Dmod + h * HDim + nt * 16 + l16] =
          (bf16_t)(o1[nt][r] * inv1[r]);
    }
}

// ---------------------------------------------------------------------------
// out_kernel: OUT = CTX @ Wout^T. R21 = R19 exact: 128x64 tile,
// single-buffered LDS DMA, grid (32,16). fp32 out.
// ---------------------------------------------------------------------------
__global__ __launch_bounds__(256) void out_kernel(
    const bf16_t* __restrict__ Actx, const bf16_t* __restrict__ Bwout,
    float* __restrict__ out)
{
  __shared__ __align__(16) bf16_t As[128 * 64];
  __shared__ __align__(16) bf16_t Bs[64 * 64];

  const int tid  = threadIdx.x;
  const int wave = tid >> 6;
  const int lane = tid & 63;
  const int quad = lane >> 4;
  const int l16  = lane & 15;
  const int wm   = (wave & 1) * 64;
  const int wn   = (wave >> 1) * 32;
  const int m0   = blockIdx.x * 128;   // x = m: same-A blocks -> same XCD
  const int n0   = blockIdx.y * 64;

  const int srow8  = lane >> 3;
  const int schunk = (lane & 7) ^ srow8;

  f32x4 acc[4][2];
#pragma unroll
  for (int i = 0; i < 4; ++i)
#pragma unroll
    for (int j = 0; j < 2; ++j)
#pragma unroll
      for (int e = 0; e < 4; ++e) acc[i][j][e] = 0.0f;

  for (int kt = 0; kt < 16; ++kt) {
    const int k0 = kt * 64;
    __syncthreads();
#pragma unroll
    for (int i = 0; i < 4; ++i) {
      const int rb = wave * 32 + i * 8;
      async_ld16(&Actx[(size_t)(m0 + rb + srow8) * Dmod + k0 + schunk * 8], &As[rb * 64]);
    }
#pragma unroll
    for (int i = 0; i < 2; ++i) {
      const int rb = wave * 16 + i * 8;
      async_ld16(&Bwout[(size_t)(n0 + rb + srow8) * Dmod + k0 + schunk * 8], &Bs[rb * 64]);
    }
    __syncthreads();

    bf16x8 af[4][2], bfr[2][2];
#pragma unroll
    for (int mt = 0; mt < 4; ++mt) {
      const int row = wm + mt * 16 + l16;
      af[mt][0] = *(const bf16x8*)&As[swz(row, quad)];
      af[mt][1] = *(const bf16x8*)&As[swz(row, quad + 4)];
    }
#pragma unroll
    for (int nt = 0; nt < 2; ++nt) {
      const int row = wn + nt * 16 + l16;
      bfr[nt][0] = *(const bf16x8*)&Bs[swz(row, quad)];
      bfr[nt][1] = *(const bf16x8*)&Bs[swz(row, quad + 4)];
    }
#pragma unroll
    for (int mt = 0; mt < 4; ++mt)
#pragma unroll
      for (int nt = 0; nt < 2; ++nt) {
        acc[mt][nt] = MFMA_BF16(af[mt][0], bfr[nt][0], acc[mt][nt]);
        acc[mt][nt] = MFMA_BF16(af[mt][1], bfr[nt][1], acc[mt][nt]);
      }
  }

#pragma unroll
  for (int mt = 0; mt < 4; ++mt) {
    const int grb = m0 + wm + mt * 16 + quad * 4;
#pragma unroll
    for (int nt = 0; nt < 2; ++nt) {
      const int gc = n0 + wn + nt * 16 + l16;
#pragma unroll
      for (int r = 0; r < 4; ++r)
        out[(size_t)(grb + r) * Dmod + gc] = acc[mt][nt][r];
    }
  }
}

// ---------------------------------------------------------------------------
extern "C" void kernel_launch(void* const* d_in, const int* in_sizes, int n_in,
                              void* d_out, int out_size, void* d_ws, size_t ws_size,
                              hipStream_t stream) {
  (void)in_sizes; (void)n_in; (void)out_size; (void)ws_size;
  const float* Q    = (const float*)d_in[0];
  const float* K    = (const float*)d_in[1];
  const float* V    = (const float*)d_in[2];
  const float* wq   = (const float*)d_in[5];
  const float* wk   = (const float*)d_in[6];
  const float* wv   = (const float*)d_in[7];
  const float* wout = (const float*)d_in[8];
  float* out = (float*)d_out;

  bf16_t* wsb = (bf16_t*)d_ws;
  bf16_t* Qbf   = wsb;
  bf16_t* Kbf   = wsb + 4 * M1;
  bf16_t* Vbf   = wsb + 8 * M1;
  bf16_t* wqb   = wsb + 12 * M1;
  bf16_t* wkb   = wsb + 13 * M1;
  bf16_t* wvb   = wsb + 14 * M1;
  bf16_t* woutb = wsb + 15 * M1;
  bf16_t* qp    = wsb + 16 * M1;
  bf16_t* kp    = wsb + 20 * M1;
  bf16_t* vp    = wsb + 24 * M1;
  bf16_t* cws   = wsb;  // ctx reuses Qbf region (Qbf dead after proj)

  cvt_kernel<<<dim3(512, 1, 16), 256, 0, stream>>>(Q, K, V, wq, wk, wv, wout, wsb);
  proj_kernel<<<dim3(32, 16, 3), 256, 0, stream>>>(Qbf, Kbf, Vbf, wqb, wkb, wvb, qp, kp, vp);
  attn_kernel<<<dim3(32, 16), 256, 0, stream>>>(qp, kp, vp, cws);
  out_kernel<<<dim3(32, 16), 256, 0, stream>>>(cws, woutb, out);
}

// Round 9
// 202.181 us; speedup vs baseline: 1.1660x; 1.0467x over previous
//
#include <hip/hip_runtime.h>
#include <stdint.h>
#include <stddef.h>

typedef __bf16 bf16_t;
typedef bf16_t bf16x4 __attribute__((ext_vector_type(4)));
typedef bf16_t bf16x8 __attribute__((ext_vector_type(8)));
typedef float f32x4 __attribute__((ext_vector_type(4)));

#define MFMA_BF16(A_, B_, C_) __builtin_amdgcn_mfma_f32_16x16x32_bf16(A_, B_, C_, 0, 0, 0)

static constexpr int Lseq = 2048;
static constexpr int Dmod = 1024;
static constexpr int Hn   = 16;
static constexpr int HDim = 64;
static constexpr size_t M1 = 1u << 20;  // 1M elements

// XOR-swizzled offset (elements) into a [rows][64] bf16 tile, 16B chunks
__device__ __forceinline__ int swz(int row, int chunk) {
  return row * 64 + ((chunk ^ (row & 7)) << 3);
}

// async global->LDS DMA, 16B per lane, wave-uniform LDS base
__device__ __forceinline__ void async_ld16(const bf16_t* g, bf16_t* l) {
  __builtin_amdgcn_global_load_lds(
      (const __attribute__((address_space(1))) void*)g,
      (__attribute__((address_space(3))) void*)l, 16, 0, 0);
}

// ---------------------------------------------------------------------------
// cvt_kernel: fp32 -> bf16, 16B stores. wq additionally pre-scaled by
// 0.125*log2(e) so attention scores arrive ready for exp2 (no per-elem mul).
// ---------------------------------------------------------------------------
__global__ __launch_bounds__(256) void cvt_kernel(
    const float* __restrict__ Q, const float* __restrict__ K,
    const float* __restrict__ V, const float* __restrict__ wq,
    const float* __restrict__ wk, const float* __restrict__ wv,
    const float* __restrict__ wout, bf16_t* __restrict__ wsb)
{
  const int s = blockIdx.z;
  const float* __restrict__ src;
  if      (s < 4)   src = Q    + (size_t)s * M1;
  else if (s < 8)   src = K    + (size_t)(s - 4) * M1;
  else if (s < 12)  src = V    + (size_t)(s - 8) * M1;
  else if (s == 12) src = wq;
  else if (s == 13) src = wk;
  else if (s == 14) src = wv;
  else              src = wout;
  bf16_t* __restrict__ dst = wsb + (size_t)s * M1;
  const float scale = (s == 12) ? 0.18033688f : 1.0f;  // 0.125 * log2(e)

  const int idx = blockIdx.x * 256 + threadIdx.x;  // 0..131071 (1M/8)
  float4 a = ((const float4*)src)[idx * 2];
  float4 b = ((const float4*)src)[idx * 2 + 1];
  bf16x8 o;
  o[0] = (bf16_t)(a.x * scale); o[1] = (bf16_t)(a.y * scale);
  o[2] = (bf16_t)(a.z * scale); o[3] = (bf16_t)(a.w * scale);
  o[4] = (bf16_t)(b.x * scale); o[5] = (bf16_t)(b.y * scale);
  o[6] = (bf16_t)(b.z * scale); o[7] = (bf16_t)(b.w * scale);
  ((bf16x8*)dst)[idx] = o;
}

// ---------------------------------------------------------------------------
// proj_kernel: all-bf16 GEMM P = X @ W^T. Measured-best config (43.6 µs):
// 128x64 tile, BK=64, single-buffered LDS DMA, 1536 blocks = 6/CU,
// TLP-hidden. (128x128, dbuf, and direct-global-B all measured slower.)
//   z=0 -> q [B,H,L,HD]; z=1 -> k [B,H,L,HD]; z=2 -> v [B,H,HD,L]
// ---------------------------------------------------------------------------
__global__ __launch_bounds__(256) void proj_kernel(
    const bf16_t* __restrict__ Qbf, const bf16_t* __restrict__ Kbf,
    const bf16_t* __restrict__ Vbf, const bf16_t* __restrict__ wqb,
    const bf16_t* __restrict__ wkb, const bf16_t* __restrict__ wvb,
    bf16_t* __restrict__ qo, bf16_t* __restrict__ ko, bf16_t* __restrict__ vo)
{
  const int z = blockIdx.z;
  const bf16_t* __restrict__ A  = (z == 0) ? Qbf : (z == 1) ? Kbf : Vbf;
  const bf16_t* __restrict__ Bw = (z == 0) ? wqb : (z == 1) ? wkb : wvb;
  bf16_t* __restrict__ dst      = (z == 0) ? qo  : (z == 1) ? ko  : vo;

  __shared__ __align__(16) bf16_t As[128 * 64];  // 16 KB
  __shared__ __align__(16) bf16_t Bs[64 * 64];   //  8 KB

  const int tid  = threadIdx.x;
  const int wave = tid >> 6;
  const int lane = tid & 63;
  const int quad = lane >> 4;
  const int l16  = lane & 15;
  const int wm   = (wave & 1) * 64;
  const int wn   = (wave >> 1) * 32;
  const int m0   = blockIdx.x * 128;   // x = m (32): same-A blocks -> same XCD
  const int n0   = blockIdx.y * 64;    // y = n (16)

  const int srow8  = lane >> 3;
  const int schunk = (lane & 7) ^ srow8;

  f32x4 acc[4][2];
#pragma unroll
  for (int i = 0; i < 4; ++i)
#pragma unroll
    for (int j = 0; j < 2; ++j)
#pragma unroll
      for (int e = 0; e < 4; ++e) acc[i][j][e] = 0.0f;

  for (int kt = 0; kt < 16; ++kt) {
    const int k0 = kt * 64;
    __syncthreads();  // LDS reads of previous iter done
#pragma unroll
    for (int i = 0; i < 4; ++i) {
      const int rb = wave * 32 + i * 8;
      async_ld16(&A[(size_t)(m0 + rb + srow8) * Dmod + k0 + schunk * 8], &As[rb * 64]);
    }
#pragma unroll
    for (int i = 0; i < 2; ++i) {
      const int rb = wave * 16 + i * 8;
      async_ld16(&Bw[(size_t)(n0 + rb + srow8) * Dmod + k0 + schunk * 8], &Bs[rb * 64]);
    }
    __syncthreads();  // DMA drained

    bf16x8 af[4][2], bfr[2][2];
#pragma unroll
    for (int mt = 0; mt < 4; ++mt) {
      const int row = wm + mt * 16 + l16;
      af[mt][0] = *(const bf16x8*)&As[swz(row, quad)];
      af[mt][1] = *(const bf16x8*)&As[swz(row, quad + 4)];
    }
#pragma unroll
    for (int nt = 0; nt < 2; ++nt) {
      const int row = wn + nt * 16 + l16;
      bfr[nt][0] = *(const bf16x8*)&Bs[swz(row, quad)];
      bfr[nt][1] = *(const bf16x8*)&Bs[swz(row, quad + 4)];
    }
#pragma unroll
    for (int mt = 0; mt < 4; ++mt)
#pragma unroll
      for (int nt = 0; nt < 2; ++nt) {
        acc[mt][nt] = MFMA_BF16(af[mt][0], bfr[nt][0], acc[mt][nt]);
        acc[mt][nt] = MFMA_BF16(af[mt][1], bfr[nt][1], acc[mt][nt]);
      }
  }

#pragma unroll
  for (int mt = 0; mt < 4; ++mt) {
    const int grb = m0 + wm + mt * 16 + quad * 4;
    const int bb  = grb >> 11;
    const int lb  = grb & 2047;
#pragma unroll
    for (int nt = 0; nt < 2; ++nt) {
      const int gc = n0 + wn + nt * 16 + l16;
      const int h  = gc >> 6;
      const int hd = gc & 63;
      if (z == 2) {
        bf16x4 pk;
#pragma unroll
        for (int r = 0; r < 4; ++r) pk[r] = (bf16_t)acc[mt][nt][r];
        *(bf16x4*)&dst[(((size_t)(bb * Hn + h) * HDim + hd) << 11) + lb] = pk;
      } else {
#pragma unroll
        for (int r = 0; r < 4; ++r)
          dst[(((size_t)(bb * Hn + h) * Lseq + lb + r) << 6) + hd] = (bf16_t)acc[mt][nt][r];
      }
    }
  }
}

// ---------------------------------------------------------------------------
// attn_kernel: causal flash attention — R22: the R20 attn variant (64-row
// q-blocks: 4 waves x 16 q-rows, grid (32,32)=1024 blocks, LDS 41 KB ->
// 3 blocks/CU + backfill pool + 2x finer LPT) re-measured CLEAN (its R20
// timing was masked by the proj regression; correctness already verified).
// Rationale: attn is latency-bound (all pipes <20%, occ 11.8% at the
// 2-blocks/CU hard cap of the 128-row version) -> residency is the binding
// constraint, worth giving up the 2x K/V-fragment amortization.
// dbuf K/V DMA, Ps-LDS round-trip, setprio (+10% measured), XCD=bh%8.
// ---------------------------------------------------------------------------
__global__ __launch_bounds__(256, 3) void attn_kernel(
    const bf16_t* __restrict__ q, const bf16_t* __restrict__ k,
    const bf16_t* __restrict__ v, bf16_t* __restrict__ ctx)
{
  const int bh = blockIdx.x;            // 0..31  (fast dim -> XCD = bh%8)
  const int qt = 31 - blockIdx.y;       // LPT: longest blocks first
  const int bb = bh >> 4;
  const int h  = bh & 15;
  const int q0 = qt * 64;

  const int tid  = threadIdx.x;
  const int wave = tid >> 6;
  const int lane = tid & 63;
  const int quad = lane >> 4;
  const int l16  = lane & 15;

  __shared__ __align__(16) bf16_t Ks[2][64 * 64];  // 16 KB
  __shared__ __align__(16) bf16_t Vs[2][64 * 64];  // 16 KB
  __shared__ __align__(16) bf16_t Ps[4][16][72];   //  9 KB

  const bf16_t* __restrict__ qb = q + (size_t)bh * (Lseq * HDim);
  const bf16_t* __restrict__ kb = k + (size_t)bh * (Lseq * HDim);
  const bf16_t* __restrict__ vb = v + (size_t)bh * (HDim * Lseq);

  const int srow8  = lane >> 3;
  const int schunk = (lane & 7) ^ srow8;

  bf16x8 ones;
#pragma unroll
  for (int i = 0; i < 8; ++i) ones[i] = (bf16_t)1.0f;

  const int qlo = q0 + wave * 16;       // wave's first query row
  const int qrow = qlo + l16;
  bf16x8 qf0 = *(const bf16x8*)&qb[(size_t)qrow * HDim + quad * 8];
  bf16x8 qf1 = *(const bf16x8*)&qb[(size_t)qrow * HDim + 32 + quad * 8];

  // strength-reduced per-lane DMA source pointers (advance per k-tile)
  const bf16_t* ks0 = kb + (size_t)(wave * 16 + srow8) * HDim + schunk * 8;
  const bf16_t* ks1 = ks0 + (size_t)8 * HDim;
  const bf16_t* vs0 = vb + (size_t)(wave * 16 + srow8) * Lseq + schunk * 8;
  const bf16_t* vs1 = vs0 + (size_t)8 * Lseq;
  const int ldo0 = (wave * 16) * 64;
  const int ldo1 = (wave * 16 + 8) * 64;

  // hoisted swizzled LDS read offsets (same rows for Ks and Vs)
  int ro0[4], ro1[4];
#pragma unroll
  for (int nt = 0; nt < 4; ++nt) {
    const int row = nt * 16 + l16;
    ro0[nt] = swz(row, quad);
    ro1[nt] = swz(row, quad + 4);
  }

  f32x4 o[4];
  f32x4 lacc;
#pragma unroll
  for (int e = 0; e < 4; ++e) lacc[e] = 0.0f;
#pragma unroll
  for (int nt = 0; nt < 4; ++nt)
#pragma unroll
    for (int e = 0; e < 4; ++e) o[nt][e] = 0.0f;

  // preload tile jt=0 into buffer 0
  async_ld16(ks0, &Ks[0][ldo0]);
  async_ld16(ks1, &Ks[0][ldo1]);
  async_ld16(vs0, &Vs[0][ldo0]);
  async_ld16(vs1, &Vs[0][ldo1]);
  ks0 += (size_t)64 * HDim; ks1 += (size_t)64 * HDim;
  vs0 += 64;                vs1 += 64;

  for (int jt = 0; jt <= qt; ++jt) {
    const int cur = jt & 1;
    __syncthreads();  // drains cur's DMA; alt's readers (iter jt-1) done

    if (jt < qt) {    // prefetch next tile into alt; in flight under compute
      async_ld16(ks0, &Ks[cur ^ 1][ldo0]);
      async_ld16(ks1, &Ks[cur ^ 1][ldo1]);
      async_ld16(vs0, &Vs[cur ^ 1][ldo0]);
      async_ld16(vs1, &Vs[cur ^ 1][ldo1]);
      ks0 += (size_t)64 * HDim; ks1 += (size_t)64 * HDim;
      vs0 += 64;                vs1 += 64;
    }

    // S^T = K Q^T  (m=key, n=query); scores pre-scaled for exp2
    if (jt == qt) {   // diagonal tile (only the last one for 64-row blocks)
      const int db = qlo + l16 - jt * 64;  // mask iff key_local > db
#pragma unroll
      for (int nt = 0; nt < 4; ++nt) {
        bf16x8 kf0 = *(const bf16x8*)&Ks[cur][ro0[nt]];
        bf16x8 kf1 = *(const bf16x8*)&Ks[cur][ro1[nt]];
        f32x4 s;
#pragma unroll
        for (int e = 0; e < 4; ++e) s[e] = 0.0f;
        s = MFMA_BF16(kf0, qf0, s);
        s = MFMA_BF16(kf1, qf1, s);
        bf16x4 pk;
#pragma unroll
        for (int r = 0; r < 4; ++r) {
          const int kl = nt * 16 + quad * 4 + r;
          float val = (kl > db) ? -1e30f : s[r];
          pk[r] = (bf16_t)__builtin_amdgcn_exp2f(val);
        }
        *(bf16x4*)&Ps[wave][l16][nt * 16 + quad * 4] = pk;
      }
    } else {
#pragma unroll
      for (int nt = 0; nt < 4; ++nt) {
        bf16x8 kf0 = *(const bf16x8*)&Ks[cur][ro0[nt]];
        bf16x8 kf1 = *(const bf16x8*)&Ks[cur][ro1[nt]];
        f32x4 s;
#pragma unroll
        for (int e = 0; e < 4; ++e) s[e] = 0.0f;
        s = MFMA_BF16(kf0, qf0, s);
        s = MFMA_BF16(kf1, qf1, s);
        bf16x4 pk;
#pragma unroll
        for (int r = 0; r < 4; ++r)
          pk[r] = (bf16_t)__builtin_amdgcn_exp2f(s[r]);
        *(bf16x4*)&Ps[wave][l16][nt * 16 + quad * 4] = pk;
      }
    }

    // P fragments (A-layout) — wave-local LDS round-trip
    bf16x8 pf0 = *(const bf16x8*)&Ps[wave][l16][quad * 8];
    bf16x8 pf1 = *(const bf16x8*)&Ps[wave][l16][32 + quad * 8];

    // dense MFMA cluster: prioritize this wave on the CU scheduler (T5)
    __builtin_amdgcn_s_setprio(1);

    lacc = MFMA_BF16(pf0, ones, lacc);
    lacc = MFMA_BF16(pf1, ones, lacc);

#pragma unroll
    for (int nt = 0; nt < 4; ++nt) {
      bf16x8 vf0 = *(const bf16x8*)&Vs[cur][ro0[nt]];
      bf16x8 vf1 = *(const bf16x8*)&Vs[cur][ro1[nt]];
      o[nt] = MFMA_BF16(pf0, vf0, o[nt]);
      o[nt] = MFMA_BF16(pf1, vf1, o[nt]);
    }

    __builtin_amdgcn_s_setprio(0);
  }

  float inv[4];
#pragma unroll
  for (int r = 0; r < 4; ++r) inv[r] = 1.0f / lacc[r];
#pragma unroll
  for (int nt = 0; nt < 4; ++nt)
#pragma unroll
    for (int r = 0; r < 4; ++r) {
      const int gq = q0 + wave * 16 + quad * 4 + r;
      ctx[(size_t)(bb * Lseq + gq) * Dmod + h * HDim + nt * 16 + l16] =
          (bf16_t)(o[nt][r] * inv[r]);
    }
}

// ---------------------------------------------------------------------------
// out_kernel: OUT = CTX @ Wout^T. Measured-best config: 128x64 tile,
// single-buffered LDS DMA, grid (32,16). fp32 out.
// ---------------------------------------------------------------------------
__global__ __launch_bounds__(256) void out_kernel(
    const bf16_t* __restrict__ Actx, const bf16_t* __restrict__ Bwout,
    float* __restrict__ out)
{
  __shared__ __align__(16) bf16_t As[128 * 64];
  __shared__ __align__(16) bf16_t Bs[64 * 64];

  const int tid  = threadIdx.x;
  const int wave = tid >> 6;
  const int lane = tid & 63;
  const int quad = lane >> 4;
  const int l16  = lane & 15;
  const int wm   = (wave & 1) * 64;
  const int wn   = (wave >> 1) * 32;
  const int m0   = blockIdx.x * 128;   // x = m: same-A blocks -> same XCD
  const int n0   = blockIdx.y * 64;

  const int srow8  = lane >> 3;
  const int schunk = (lane & 7) ^ srow8;

  f32x4 acc[4][2];
#pragma unroll
  for (int i = 0; i < 4; ++i)
#pragma unroll
    for (int j = 0; j < 2; ++j)
#pragma unroll
      for (int e = 0; e < 4; ++e) acc[i][j][e] = 0.0f;

  for (int kt = 0; kt < 16; ++kt) {
    const int k0 = kt * 64;
    __syncthreads();
#pragma unroll
    for (int i = 0; i < 4; ++i) {
      const int rb = wave * 32 + i * 8;
      async_ld16(&Actx[(size_t)(m0 + rb + srow8) * Dmod + k0 + schunk * 8], &As[rb * 64]);
    }
#pragma unroll
    for (int i = 0; i < 2; ++i) {
      const int rb = wave * 16 + i * 8;
      async_ld16(&Bwout[(size_t)(n0 + rb + srow8) * Dmod + k0 + schunk * 8], &Bs[rb * 64]);
    }
    __syncthreads();

    bf16x8 af[4][2], bfr[2][2];
#pragma unroll
    for (int mt = 0; mt < 4; ++mt) {
      const int row = wm + mt * 16 + l16;
      af[mt][0] = *(const bf16x8*)&As[swz(row, quad)];
      af[mt][1] = *(const bf16x8*)&As[swz(row, quad + 4)];
    }
#pragma unroll
    for (int nt = 0; nt < 2; ++nt) {
      const int row = wn + nt * 16 + l16;
      bfr[nt][0] = *(const bf16x8*)&Bs[swz(row, quad)];
      bfr[nt][1] = *(const bf16x8*)&Bs[swz(row, quad + 4)];
    }
#pragma unroll
    for (int mt = 0; mt < 4; ++mt)
#pragma unroll
      for (int nt = 0; nt < 2; ++nt) {
        acc[mt][nt] = MFMA_BF16(af[mt][0], bfr[nt][0], acc[mt][nt]);
        acc[mt][nt] = MFMA_BF16(af[mt][1], bfr[nt][1], acc[mt][nt]);
      }
  }

#pragma unroll
  for (int mt = 0; mt < 4; ++mt) {
    const int grb = m0 + wm + mt * 16 + quad * 4;
#pragma unroll
    for (int nt = 0; nt < 2; ++nt) {
      const int gc = n0 + wn + nt * 16 + l16;
#pragma unroll
      for (int r = 0; r < 4; ++r)
        out[(size_t)(grb + r) * Dmod + gc] = acc[mt][nt][r];
    }
  }
}

// ---------------------------------------------------------------------------
extern "C" void kernel_launch(void* const* d_in, const int* in_sizes, int n_in,
                              void* d_out, int out_size, void* d_ws, size_t ws_size,
                              hipStream_t stream) {
  (void)in_sizes; (void)n_in; (void)out_size; (void)ws_size;
  const float* Q    = (const float*)d_in[0];
  const float* K    = (const float*)d_in[1];
  const float* V    = (const float*)d_in[2];
  const float* wq   = (const float*)d_in[5];
  const float* wk   = (const float*)d_in[6];
  const float* wv   = (const float*)d_in[7];
  const float* wout = (const float*)d_in[8];
  float* out = (float*)d_out;

  bf16_t* wsb = (bf16_t*)d_ws;
  bf16_t* Qbf   = wsb;
  bf16_t* Kbf   = wsb + 4 * M1;
  bf16_t* Vbf   = wsb + 8 * M1;
  bf16_t* wqb   = wsb + 12 * M1;
  bf16_t* wkb   = wsb + 13 * M1;
  bf16_t* wvb   = wsb + 14 * M1;
  bf16_t* woutb = wsb + 15 * M1;
  bf16_t* qp    = wsb + 16 * M1;
  bf16_t* kp    = wsb + 20 * M1;
  bf16_t* vp    = wsb + 24 * M1;
  bf16_t* cws   = wsb;  // ctx reuses Qbf region (Qbf dead after proj)

  cvt_kernel<<<dim3(512, 1, 16), 256, 0, stream>>>(Q, K, V, wq, wk, wv, wout, wsb);
  proj_kernel<<<dim3(32, 16, 3), 256, 0, stream>>>(Qbf, Kbf, Vbf, wqb, wkb, wvb, qp, kp, vp);
  attn_kernel<<<dim3(32, 32), 256, 0, stream>>>(qp, kp, vp, cws);
  out_kernel<<<dim3(32, 16), 256, 0, stream>>>(cws, woutb, out);
}